// Round 1
// baseline (298.501 us; speedup 1.0000x reference)
//
#include <hip/hip_runtime.h>

#define NN 64
#define NN1 65
#define BB 8
#define CC 3
#define HH 64
#define WW 64
#define EE 513
#define EQF -0.1f

#define TH 32          // output rows per conv block
#define TROWS 35       // TH + 3 input rows
#define TWID 68        // padded tile width (67 used)
#define IMG (HH*WW)    // 4096
#define CHW (CC*IMG)   // 12288
#define BCHW (BB*CHW)  // 98304
#define TOT_F (NN1*BCHW)   // 6389760
#define TOT_F4 (TOT_F/4)   // 1597440
#define NREG_F4 ((NN*BCHW)/4) // 1572864

typedef unsigned short u16;

// ---------------- CSR build (deterministic, one block) ----------------
__global__ __launch_bounds__(256) void build_csr_k(const int* __restrict__ dst,
                                                   int* __restrict__ csr_off,
                                                   int* __restrict__ csr_list) {
  __shared__ int sdst[EE];
  __shared__ int scnt[NN];
  __shared__ int soff[NN + 1];
  int tid = threadIdx.x;
  for (int e = tid; e < EE; e += 256) sdst[e] = dst[e];
  __syncthreads();
  if (tid < NN) {
    int c = 0;
    for (int e = 0; e < EE; ++e) c += (sdst[e] == tid) ? 1 : 0;
    scnt[tid] = c;
  }
  __syncthreads();
  if (tid == 0) {
    int s = 0;
    for (int n2 = 0; n2 < NN; ++n2) { soff[n2] = s; s += scnt[n2]; }
    soff[NN] = s;
  }
  __syncthreads();
  if (tid < NN) {
    int p = soff[tid];
    for (int e = 0; e < EE; ++e)
      if (sdst[e] == tid) csr_list[p++] = e;   // preserves edge order (deterministic sums)
  }
  if (tid <= NN) csr_off[tid] = soff[tid];
}

// ---------------- acts = sigmoid(states+noise) (bf16), node-N out copy ----------------
__global__ __launch_bounds__(256) void prep_k(const float4* __restrict__ st4,
                                              const float4* __restrict__ nz4,
                                              ushort4* __restrict__ acts4,
                                              float4* __restrict__ out4) {
  int i = blockIdx.x * 256 + threadIdx.x;
  if (i >= TOT_F4) return;
  float4 s = st4[i];
  float4 z = nz4[i];
  float a0 = 1.0f / (1.0f + __expf(-(s.x + z.x)));
  float a1 = 1.0f / (1.0f + __expf(-(s.y + z.y)));
  float a2 = 1.0f / (1.0f + __expf(-(s.z + z.z)));
  float a3 = 1.0f / (1.0f + __expf(-(s.w + z.w)));
  union { float f; unsigned u; } c0, c1, c2, c3;
  c0.f = a0; c1.f = a1; c2.f = a2; c3.f = a3;
  ushort4 r;
  r.x = (u16)((c0.u + 0x7fffu + ((c0.u >> 16) & 1u)) >> 16);
  r.y = (u16)((c1.u + 0x7fffu + ((c1.u >> 16) & 1u)) >> 16);
  r.z = (u16)((c2.u + 0x7fffu + ((c2.u >> 16) & 1u)) >> 16);
  r.w = (u16)((c3.u + 0x7fffu + ((c3.u >> 16) & 1u)) >> 16);
  acts4[i] = r;
  if (i >= NREG_F4) out4[i] = s;   // virtual node N: out = states (agg is 0 there)
}

// ---------------- per-node conv + scatter + resistive epilogue ----------------
__global__ __launch_bounds__(256) void conv_k(const float* __restrict__ states,
                                              const float* __restrict__ res,
                                              const u16* __restrict__ acts,
                                              const float* __restrict__ conv_w,
                                              const float* __restrict__ conv_b,
                                              const int* __restrict__ srcArr,
                                              const int* __restrict__ csr_off,
                                              const int* __restrict__ csr_list,
                                              float* __restrict__ out) {
  __shared__ float tile[3 * TROWS * TWID];   // 28560 B
  __shared__ float wt[3][4][16];             // [ci][kw][kh*3+co], padded rows
  __shared__ float wbias[4];

  int bid = blockIdx.x;
  int ht = bid & 1;
  int b  = (bid >> 1) & 7;
  int n  = bid >> 4;
  int tid = threadIdx.x;
  int w  = tid & 63;
  int hg = tid >> 6;            // 0..3, each owns 8 output rows
  int hbase = ht * TH + hg * 8;

  float acc[8][3];
  #pragma unroll
  for (int px = 0; px < 8; ++px)
    #pragma unroll
    for (int co = 0; co < 3; ++co) acc[px][co] = 0.0f;

  int e0 = csr_off[n], e1 = csr_off[n + 1];
  for (int ei = e0; ei < e1; ++ei) {
    int e = csr_list[ei];
    int s = srcArr[e];
    __syncthreads();   // protect previous iteration's tile reads

    // stage acts tile (3 ci x 35 rows x 67 cols, zero-padded)
    const u16* ap = acts + (size_t)s * BCHW + (size_t)b * CHW;
    for (int idx = tid; idx < 3 * TROWS * TWID; idx += 256) {
      int ci  = idx / (TROWS * TWID);
      int rem = idx - ci * (TROWS * TWID);
      int r   = rem / TWID;
      int c   = rem - r * TWID;
      int hin = ht * TH + r - 1;
      int win = c - 1;
      float v = 0.0f;
      if ((unsigned)hin < (unsigned)HH && (unsigned)win < (unsigned)WW) {
        unsigned u = ap[ci * IMG + hin * WW + win];
        union { unsigned uu; float ff; } cv; cv.uu = u << 16;
        v = cv.ff;
      }
      tile[idx] = v;
    }
    // stage weights transposed: wt[ci][kw][kh*3+co]
    if (tid < 144) {
      int co = tid / 48;
      int ci = (tid >> 4) % 3;
      int kh = (tid >> 2) & 3;
      int kw = tid & 3;
      wt[ci][kw][kh * 3 + co] = conv_w[e * 144 + tid];
    }
    if (tid < 3) wbias[tid] = conv_b[e * 3 + tid];
    __syncthreads();

    float b0 = wbias[0], b1 = wbias[1], b2 = wbias[2];
    #pragma unroll
    for (int px = 0; px < 8; ++px) { acc[px][0] += b0; acc[px][1] += b1; acc[px][2] += b2; }

    #pragma unroll
    for (int ci = 0; ci < 3; ++ci) {
      const float* tp = &tile[ci * (TROWS * TWID) + (hg * 8) * TWID + w];
      #pragma unroll
      for (int kw = 0; kw < 4; ++kw) {
        float a[11];
        #pragma unroll
        for (int j = 0; j < 11; ++j) a[j] = tp[j * TWID + kw];
        const float4* wp = (const float4*)(&wt[ci][kw][0]);
        float4 w0 = wp[0], w1 = wp[1], w2 = wp[2];
        float wv[12] = {w0.x, w0.y, w0.z, w0.w, w1.x, w1.y, w1.z, w1.w, w2.x, w2.y, w2.z, w2.w};
        #pragma unroll
        for (int kh = 0; kh < 4; ++kh) {
          #pragma unroll
          for (int co = 0; co < 3; ++co) {
            float wgt = wv[kh * 3 + co];
            #pragma unroll
            for (int px = 0; px < 8; ++px) acc[px][co] += a[px + kh] * wgt;
          }
        }
      }
    }
  }

  // epilogue: out = states + agg + |res|*(EQ - states)
  #pragma unroll
  for (int co = 0; co < 3; ++co) {
    #pragma unroll
    for (int px = 0; px < 8; ++px) {
      int o = ((n * BB + b) * CC + co) * IMG + (hbase + px) * WW + w;
      float st = states[o];
      float rv = res[o];
      out[o] = st + fabsf(rv) * (EQF - st) + acc[px][co];
    }
  }
}

extern "C" void kernel_launch(void* const* d_in, const int* in_sizes, int n_in,
                              void* d_out, int out_size, void* d_ws, size_t ws_size,
                              hipStream_t stream) {
  const float* states = (const float*)d_in[0];
  const float* noise  = (const float*)d_in[1];
  const float* conv_w = (const float*)d_in[2];
  const float* conv_b = (const float*)d_in[3];
  const float* res    = (const float*)d_in[4];
  const int*   src    = (const int*)d_in[5];
  const int*   dst    = (const int*)d_in[6];
  float* out = (float*)d_out;

  u16* acts = (u16*)d_ws;                                  // 12,779,520 B
  int* csr_off  = (int*)((char*)d_ws + (size_t)TOT_F * 2); // 65 ints
  int* csr_list = csr_off + 80;                            // 513 ints

  build_csr_k<<<1, 256, 0, stream>>>(dst, csr_off, csr_list);
  prep_k<<<TOT_F4 / 256, 256, 0, stream>>>((const float4*)states, (const float4*)noise,
                                           (ushort4*)acts, (float4*)d_out);
  conv_k<<<NN * BB * (HH / TH), 256, 0, stream>>>(states, res, acts, conv_w, conv_b,
                                                  src, csr_off, csr_list, (float*)d_out);
}

// Round 2
// 145.130 us; speedup vs baseline: 2.0568x; 2.0568x over previous
//
#include <hip/hip_runtime.h>

#define NN 64
#define NN1 65
#define BB 8
#define CC 3
#define HH 64
#define WW 64
#define EE 513
#define EQF -0.1f

#define IMG (HH*WW)    // 4096
#define CHW (CC*IMG)   // 12288
#define BCHW (BB*CHW)  // 98304
#define TOT_F (NN1*BCHW)   // 6389760
#define TOT_F4 (TOT_F/4)   // 1597440
#define NREG_F4 ((NN*BCHW)/4) // 1572864

#define TH 16          // output rows per conv block
#define TR 19          // TH + 3 input rows
#define TS 72          // tile row stride in floats (16B-aligned rows: 288B)
#define TILE_F (3*TR*TS)   // 4104 floats = 16416 B
#define NSLICE (3*TR)      // 57 (ci,row) slices

typedef unsigned short u16;

// ---------------- CSR build (deterministic, one block) ----------------
__global__ __launch_bounds__(256) void build_csr_k(const int* __restrict__ dst,
                                                   int* __restrict__ csr_off,
                                                   int* __restrict__ csr_list) {
  __shared__ int sdst[EE];
  __shared__ int scnt[NN];
  __shared__ int soff[NN + 1];
  int tid = threadIdx.x;
  for (int e = tid; e < EE; e += 256) sdst[e] = dst[e];
  __syncthreads();
  if (tid < NN) {
    int c = 0;
    for (int e = 0; e < EE; ++e) c += (sdst[e] == tid) ? 1 : 0;
    scnt[tid] = c;
  }
  __syncthreads();
  if (tid == 0) {
    int s = 0;
    for (int n2 = 0; n2 < NN; ++n2) { soff[n2] = s; s += scnt[n2]; }
    soff[NN] = s;
  }
  __syncthreads();
  if (tid < NN) {
    int p = soff[tid];
    for (int e = 0; e < EE; ++e)
      if (sdst[e] == tid) csr_list[p++] = e;   // preserves edge order (deterministic sums)
  }
  if (tid <= NN) csr_off[tid] = soff[tid];
}

// ---------------- acts = sigmoid(states+noise) (bf16), node-N out copy ----------------
__global__ __launch_bounds__(256) void prep_k(const float4* __restrict__ st4,
                                              const float4* __restrict__ nz4,
                                              ushort4* __restrict__ acts4,
                                              float4* __restrict__ out4) {
  int i = blockIdx.x * 256 + threadIdx.x;
  if (i >= TOT_F4) return;
  float4 s = st4[i];
  float4 z = nz4[i];
  float a0 = 1.0f / (1.0f + __expf(-(s.x + z.x)));
  float a1 = 1.0f / (1.0f + __expf(-(s.y + z.y)));
  float a2 = 1.0f / (1.0f + __expf(-(s.z + z.z)));
  float a3 = 1.0f / (1.0f + __expf(-(s.w + z.w)));
  union { float f; unsigned u; } c0, c1, c2, c3;
  c0.f = a0; c1.f = a1; c2.f = a2; c3.f = a3;
  ushort4 r;
  r.x = (u16)((c0.u + 0x7fffu + ((c0.u >> 16) & 1u)) >> 16);
  r.y = (u16)((c1.u + 0x7fffu + ((c1.u >> 16) & 1u)) >> 16);
  r.z = (u16)((c2.u + 0x7fffu + ((c2.u >> 16) & 1u)) >> 16);
  r.w = (u16)((c3.u + 0x7fffu + ((c3.u >> 16) & 1u)) >> 16);
  acts4[i] = r;
  if (i >= NREG_F4) out4[i] = s;   // virtual node N: out = states (agg is 0 there)
}

__device__ __forceinline__ float bf2f(unsigned h) {
  union { unsigned u; float f; } c; c.u = h << 16; return c.f;
}

// ---------------- per-node conv + scatter + resistive epilogue ----------------
__global__ __launch_bounds__(256, 6) void conv_k(const float* __restrict__ states,
                                                 const float* __restrict__ res,
                                                 const u16* __restrict__ acts,
                                                 const float* __restrict__ conv_w,
                                                 const float* __restrict__ conv_b,
                                                 const int* __restrict__ srcArr,
                                                 const int* __restrict__ csr_off,
                                                 const int* __restrict__ csr_list,
                                                 float* __restrict__ out) {
  __shared__ float tile[TILE_F];   // 16416 B

  int bid = blockIdx.x;
  int ht = bid & 3;          // 4 h-tiles of 16 rows
  int b  = (bid >> 2) & 7;
  int n  = bid >> 5;
  int tid = threadIdx.x;
  int w  = tid & 63;
  int hg = tid >> 6;         // 0..3, each owns 4 output rows

  // zero tile once: pad cells stay zero forever; valid rows get overwritten per edge
  #pragma unroll
  for (int i4 = 0; i4 < 5; ++i4) {
    int idx = tid + i4 * 256;
    if (idx < TILE_F / 4) {
      float4 zz; zz.x = 0.f; zz.y = 0.f; zz.z = 0.f; zz.w = 0.f;
      *(float4*)&tile[idx * 4] = zz;
    }
  }

  // per-thread staging params (constant across edges)
  int jj4 = (tid & 15) * 4;     // col group (source cols jj4..jj4+3)
  int sl0 = tid >> 4;           // slice base within pass
  int soff[4]; int laddr[4]; bool sval[4];
  #pragma unroll
  for (int p = 0; p < 4; ++p) {
    int slice = p * 16 + sl0;
    int ci = (slice >= 38) ? 2 : ((slice >= 19) ? 1 : 0);
    int r  = slice - ci * 19;
    int hin = ht * TH + r - 1;
    sval[p]  = (slice < NSLICE) && (hin >= 0) && (hin < HH);
    soff[p]  = b * CHW + ci * IMG + hin * WW + jj4;   // u16 index within node image
    laddr[p] = (ci * TR + r) * TS + 4 + jj4;          // float index in tile (16B aligned)
  }

  float acc[4][3];
  #pragma unroll
  for (int px = 0; px < 4; ++px)
    #pragma unroll
    for (int co = 0; co < 3; ++co) acc[px][co] = 0.0f;
  float bsum0 = 0.f, bsum1 = 0.f, bsum2 = 0.f;

  int e0 = csr_off[n], e1 = csr_off[n + 1];

  ushort4 us0, us1, us2, us3;
  int e = 0;
  if (e0 < e1) {
    e = __builtin_amdgcn_readfirstlane(csr_list[e0]);
    int s = __builtin_amdgcn_readfirstlane(srcArr[e]);
    const u16* ap = acts + (size_t)s * BCHW;
    if (sval[0]) us0 = *(const ushort4*)(ap + soff[0]);
    if (sval[1]) us1 = *(const ushort4*)(ap + soff[1]);
    if (sval[2]) us2 = *(const ushort4*)(ap + soff[2]);
    if (sval[3]) us3 = *(const ushort4*)(ap + soff[3]);
  }

  for (int ei = e0; ei < e1; ++ei) {
    __syncthreads();   // previous edge's compute (and zero-init) done

    // regs -> LDS (bf16 -> f32 on write)
    if (sval[0]) { float4 f; f.x=bf2f(us0.x); f.y=bf2f(us0.y); f.z=bf2f(us0.z); f.w=bf2f(us0.w); *(float4*)&tile[laddr[0]] = f; }
    if (sval[1]) { float4 f; f.x=bf2f(us1.x); f.y=bf2f(us1.y); f.z=bf2f(us1.z); f.w=bf2f(us1.w); *(float4*)&tile[laddr[1]] = f; }
    if (sval[2]) { float4 f; f.x=bf2f(us2.x); f.y=bf2f(us2.y); f.z=bf2f(us2.z); f.w=bf2f(us2.w); *(float4*)&tile[laddr[2]] = f; }
    if (sval[3]) { float4 f; f.x=bf2f(us3.x); f.y=bf2f(us3.y); f.z=bf2f(us3.z); f.w=bf2f(us3.w); *(float4*)&tile[laddr[3]] = f; }

    int ce = e;   // current edge (uniform)

    // prefetch next edge's tile into regs (latency hides under compute)
    if (ei + 1 < e1) {
      e = __builtin_amdgcn_readfirstlane(csr_list[ei + 1]);
      int s = __builtin_amdgcn_readfirstlane(srcArr[e]);
      const u16* ap = acts + (size_t)s * BCHW;
      if (sval[0]) us0 = *(const ushort4*)(ap + soff[0]);
      if (sval[1]) us1 = *(const ushort4*)(ap + soff[1]);
      if (sval[2]) us2 = *(const ushort4*)(ap + soff[2]);
      if (sval[3]) us3 = *(const ushort4*)(ap + soff[3]);
    }

    const float* wp = conv_w + ce * 144;    // uniform -> s_load weights
    bsum0 += conv_b[ce * 3 + 0];
    bsum1 += conv_b[ce * 3 + 1];
    bsum2 += conv_b[ce * 3 + 2];

    __syncthreads();   // tile ready

    const float* tp = &tile[(hg * 4) * TS + w + 3];
    #pragma unroll
    for (int ci = 0; ci < 3; ++ci) {
      #pragma unroll
      for (int kw = 0; kw < 4; ++kw) {
        float a[7];
        #pragma unroll
        for (int j = 0; j < 7; ++j) a[j] = tp[(ci * TR + j) * TS + kw];
        #pragma unroll
        for (int kh = 0; kh < 4; ++kh) {
          #pragma unroll
          for (int co = 0; co < 3; ++co) {
            float wgt = wp[co * 48 + ci * 16 + kh * 4 + kw];
            #pragma unroll
            for (int px = 0; px < 4; ++px) acc[px][co] += a[px + kh] * wgt;
          }
        }
      }
    }
  }

  // epilogue: out = states + agg + bias_sum + |res|*(EQ - states)
  #pragma unroll
  for (int co = 0; co < 3; ++co) {
    float bs = (co == 0) ? bsum0 : ((co == 1) ? bsum1 : bsum2);
    #pragma unroll
    for (int px = 0; px < 4; ++px) {
      int o = ((n * BB + b) * CC + co) * IMG + (ht * TH + hg * 4 + px) * WW + w;
      float st = states[o];
      float rv = res[o];
      out[o] = st + fabsf(rv) * (EQF - st) + acc[px][co] + bs;
    }
  }
}

extern "C" void kernel_launch(void* const* d_in, const int* in_sizes, int n_in,
                              void* d_out, int out_size, void* d_ws, size_t ws_size,
                              hipStream_t stream) {
  const float* states = (const float*)d_in[0];
  const float* noise  = (const float*)d_in[1];
  const float* conv_w = (const float*)d_in[2];
  const float* conv_b = (const float*)d_in[3];
  const float* res    = (const float*)d_in[4];
  const int*   src    = (const int*)d_in[5];
  const int*   dst    = (const int*)d_in[6];

  u16* acts = (u16*)d_ws;                                  // 12,779,520 B
  int* csr_off  = (int*)((char*)d_ws + (size_t)TOT_F * 2); // 65 ints
  int* csr_list = csr_off + 80;                            // 513 ints

  build_csr_k<<<1, 256, 0, stream>>>(dst, csr_off, csr_list);
  prep_k<<<TOT_F4 / 256, 256, 0, stream>>>((const float4*)states, (const float4*)noise,
                                           (ushort4*)acts, (float4*)d_out);
  conv_k<<<NN * BB * (HH / TH), 256, 0, stream>>>(states, res, acts, conv_w, conv_b,
                                                  src, csr_off, csr_list, (float*)d_out);
}

// Round 3
// 102.132 us; speedup vs baseline: 2.9227x; 1.4210x over previous
//
#include <hip/hip_runtime.h>

#define NN 64
#define BB 8
#define HH 64
#define WW 64
#define EE 513
#define EQF -0.1f
#define IMG 4096
#define CHW 12288
#define BCHW 98304
#define TOT_F 6389760              // 65*98304

typedef unsigned short u16;
typedef __attribute__((ext_vector_type(8))) short bf16x8;
typedef __attribute__((ext_vector_type(4))) float f32x4;

// actsI: bf16 [node][b][h][w][ci4], node stride 131072 u16, (n,b) stride 16384
#define AI_NODE 131072
// wfrag: bf16 [E][64 lanes][8]
// tile (per wtile): [11 hl][16 w][4 ci] bf16 = 704 elems, padded t-stride 720 elems (1440 B)
#define TSTRIDE_B 1440
#define TILE_B 5760                // 4 wtiles * 1440
#define ZB_ELEMS 6656              // [8h][64w'][13]

__device__ __forceinline__ u16 f2bf(float f) {
  union { float f; unsigned u; } c; c.f = f;
  return (u16)((c.u + 0x7fffu + ((c.u >> 16) & 1u)) >> 16);
}

// ---------------- CSR build (deterministic, one block) ----------------
__global__ __launch_bounds__(256) void build_csr_k(const int* __restrict__ dst,
                                                   int* __restrict__ csr_off,
                                                   int* __restrict__ csr_list) {
  __shared__ int sdst[EE];
  __shared__ int scnt[NN];
  __shared__ int soff[NN + 1];
  int tid = threadIdx.x;
  for (int e = tid; e < EE; e += 256) sdst[e] = dst[e];
  __syncthreads();
  if (tid < NN) {
    int c = 0;
    for (int e = 0; e < EE; ++e) c += (sdst[e] == tid) ? 1 : 0;
    scnt[tid] = c;
  }
  __syncthreads();
  if (tid == 0) {
    int s = 0;
    for (int n2 = 0; n2 < NN; ++n2) { soff[n2] = s; s += scnt[n2]; }
    soff[NN] = s;
  }
  __syncthreads();
  if (tid < NN) {
    int p = soff[tid];
    for (int e = 0; e < EE; ++e)
      if (sdst[e] == tid) csr_list[p++] = e;   // preserves edge order (deterministic)
  }
  if (tid <= NN) csr_off[tid] = soff[tid];
}

// ---------------- per-edge B-fragment prep: wfrag[e][lane][j] ----------------
// B[k = g*8+j][col = lane&15], k=(kh=g)*8+(ci=j), col=(co=col>>2, kw=col&3)
__global__ __launch_bounds__(256) void wfrag_k(const float* __restrict__ conv_w,
                                               u16* __restrict__ wfrag) {
  int gid = blockIdx.x * 256 + threadIdx.x;
  if (gid >= EE * 64) return;
  int e = gid >> 6, l = gid & 63;
  int g = l >> 4, col = l & 15, co = col >> 2, kw = col & 3;
  u16 v[8];
  #pragma unroll
  for (int j = 0; j < 8; ++j) {
    float f = 0.0f;
    if (co < 3 && j < 3) f = conv_w[e * 144 + co * 48 + j * 16 + g * 4 + kw];
    v[j] = f2bf(f);
  }
  uint4 pk;
  pk.x = (unsigned)v[0] | ((unsigned)v[1] << 16);
  pk.y = (unsigned)v[2] | ((unsigned)v[3] << 16);
  pk.z = (unsigned)v[4] | ((unsigned)v[5] << 16);
  pk.w = (unsigned)v[6] | ((unsigned)v[7] << 16);
  *(uint4*)(wfrag + (size_t)gid * 8) = pk;
}

// ---------------- acts = sigmoid(states+noise) -> ci-interleaved bf16; node-N out copy ----------------
__global__ __launch_bounds__(256) void prep_k(const float* __restrict__ states,
                                              const float* __restrict__ noise,
                                              u16* __restrict__ actsI,
                                              float* __restrict__ out) {
  int idx = blockIdx.x * 256 + threadIdx.x;      // 65*8*64*16 = 532480 exact
  int w4 = idx & 15, h = (idx >> 4) & 63, b = (idx >> 10) & 7, n = idx >> 13;
  int pbase = (n * 8 + b) * CHW + h * 64 + w4 * 4;   // planar f32 base (ci stride IMG)
  float4 s0 = *(const float4*)(states + pbase);
  float4 s1 = *(const float4*)(states + pbase + IMG);
  float4 s2 = *(const float4*)(states + pbase + 2 * IMG);
  float4 z0 = *(const float4*)(noise + pbase);
  float4 z1 = *(const float4*)(noise + pbase + IMG);
  float4 z2 = *(const float4*)(noise + pbase + 2 * IMG);
  float a0[4], a1[4], a2[4];
  #pragma unroll
  for (int p = 0; p < 4; ++p) {
    float v0 = ((const float*)&s0)[p] + ((const float*)&z0)[p];
    float v1 = ((const float*)&s1)[p] + ((const float*)&z1)[p];
    float v2 = ((const float*)&s2)[p] + ((const float*)&z2)[p];
    a0[p] = 1.0f / (1.0f + __expf(-v0));
    a1[p] = 1.0f / (1.0f + __expf(-v1));
    a2[p] = 1.0f / (1.0f + __expf(-v2));
  }
  // interleaved store: [w][ci4] bf16, 4 px * 8B = 32B
  uint4 q0, q1;
  q0.x = (unsigned)f2bf(a0[0]) | ((unsigned)f2bf(a1[0]) << 16);
  q0.y = (unsigned)f2bf(a2[0]);
  q0.z = (unsigned)f2bf(a0[1]) | ((unsigned)f2bf(a1[1]) << 16);
  q0.w = (unsigned)f2bf(a2[1]);
  q1.x = (unsigned)f2bf(a0[2]) | ((unsigned)f2bf(a1[2]) << 16);
  q1.y = (unsigned)f2bf(a2[2]);
  q1.z = (unsigned)f2bf(a0[3]) | ((unsigned)f2bf(a1[3]) << 16);
  q1.w = (unsigned)f2bf(a2[3]);
  u16* dp = actsI + ((size_t)(((n * 8 + b) * 64 + h) * 64) + w4 * 4) * 4;
  *(uint4*)dp = q0;
  *(uint4*)(dp + 8) = q1;
  if (n == NN) {   // virtual node: out = states (agg is 0 there)
    *(float4*)(out + pbase) = s0;
    *(float4*)(out + pbase + IMG) = s1;
    *(float4*)(out + pbase + 2 * IMG) = s2;
  }
}

// ---------------- MFMA conv + scatter + resistive epilogue ----------------
__global__ __launch_bounds__(256, 4) void conv_k(const float* __restrict__ states,
                                                 const float* __restrict__ res,
                                                 const u16* __restrict__ actsI,
                                                 const u16* __restrict__ wfrag,
                                                 const float* __restrict__ conv_b,
                                                 const int* __restrict__ srcArr,
                                                 const int* __restrict__ csr_off,
                                                 const int* __restrict__ csr_list,
                                                 float* __restrict__ out) {
  __shared__ __align__(16) char smem[ZB_ELEMS * 4];   // 26624 B; tiles union zbuf

  const int tid = threadIdx.x;
  const int lane = tid & 63;
  const int wid = tid >> 6;
  const int bid = blockIdx.x;
  const int n = bid & 63, b = (bid >> 6) & 7, ht = bid >> 9;

  // zero both tile buffers (2*5760 B = 720 float4)
  {
    float4 zz; zz.x = 0.f; zz.y = 0.f; zz.z = 0.f; zz.w = 0.f;
    for (int i = tid; i < 720; i += 256) *(float4*)(smem + i * 16) = zz;
  }

  // staging piece params (352 pieces of 8 u16 = 16B each)
  int soffA = 0, ldsA = 0; bool vA = false;
  int soffB = 0, ldsB = 0; bool vB = false;
  {
    int q = tid;                       // piece 0
    int hl = q >> 5, c = q & 31, t = c >> 3;
    int hin = ht * 8 - 1 + hl;
    vA = (hin >= 0) && (hin < 64);
    soffA = b * 16384 + hin * 256 + (c & 31) * 8;      // u16: (b*4096+hin*64+w0)*4, w0=c*2
    ldsA = t * TSTRIDE_B + hl * 128 + (c & 7) * 16;    // bytes
    q = tid + 256;                     // piece 1 (only tid<96)
    if (q < 352) {
      hl = q >> 5; c = q & 31; t = c >> 3;
      hin = ht * 8 - 1 + hl;
      vB = (hin >= 0) && (hin < 64);
      soffB = b * 16384 + hin * 256 + (c & 31) * 8;
      ldsB = t * TSTRIDE_B + hl * 128 + (c & 7) * 16;
    }
  }
  const int aoff = (lane >> 4) * 128 + (lane & 15) * 8;   // A-read lane offset (bytes)

  f32x4 acc[2][4];
  #pragma unroll
  for (int h2 = 0; h2 < 2; ++h2)
    #pragma unroll
    for (int t = 0; t < 4; ++t) { acc[h2][t][0] = 0.f; acc[h2][t][1] = 0.f; acc[h2][t][2] = 0.f; acc[h2][t][3] = 0.f; }

  const int e0 = csr_off[n], e1 = csr_off[n + 1];
  const int cnt = e1 - e0;
  float bs0 = 0.f, bs1 = 0.f, bs2 = 0.f;

  float4 p0, p1; bf16x8 wf; float bb0 = 0.f, bb1 = 0.f, bb2 = 0.f;
  #define PREFETCH(EI) do {                                                   \
    int e_ = __builtin_amdgcn_readfirstlane(csr_list[EI]);                    \
    int s_ = __builtin_amdgcn_readfirstlane(srcArr[e_]);                      \
    const u16* base_ = actsI + (size_t)s_ * AI_NODE;                          \
    if (vA) p0 = *(const float4*)(base_ + soffA);                             \
    if (vB) p1 = *(const float4*)(base_ + soffB);                             \
    wf = *(const bf16x8*)(wfrag + ((size_t)e_ * 64 + lane) * 8);              \
    bb0 = conv_b[e_ * 3 + 0]; bb1 = conv_b[e_ * 3 + 1]; bb2 = conv_b[e_ * 3 + 2]; \
  } while (0)

  bf16x8 curB;
  if (cnt > 0) {
    PREFETCH(e0);
    // stage edge 0 into buf0
    if (vA) *(float4*)(smem + ldsA) = p0;
    if (vB) *(float4*)(smem + ldsB) = p1;
    curB = wf;
    float cb0 = bb0, cb1 = bb1, cb2 = bb2;
    if (cnt > 1) PREFETCH(e0 + 1);
    __syncthreads();   // buf0 ready (also covers zero-init)
    const int hbase = wid * 2;
    for (int i = 0; i < cnt; ++i) {
      const char* tb = smem + (i & 1) * TILE_B;
      bs0 += cb0; bs1 += cb1; bs2 += cb2;
      // stage next edge into other buffer, prefetch i+2
      if (i + 1 < cnt) {
        char* nb = smem + ((i + 1) & 1) * TILE_B;
        if (vA) *(float4*)(nb + ldsA) = p0;
        if (vB) *(float4*)(nb + ldsB) = p1;
      }
      bf16x8 nextB = wf;
      float nb0 = bb0, nb1 = bb1, nb2 = bb2;
      if (i + 2 < cnt) PREFETCH(e0 + i + 2);
      // compute current buffer
      #pragma unroll
      for (int h2 = 0; h2 < 2; ++h2) {
        #pragma unroll
        for (int t = 0; t < 4; ++t) {
          short4 d = *(const short4*)(tb + t * TSTRIDE_B + (hbase + h2) * 128 + aoff);
          bf16x8 a;
          a[0] = d.x; a[1] = d.y; a[2] = d.z; a[3] = d.w;
          a[4] = 0; a[5] = 0; a[6] = 0; a[7] = 0;
          acc[h2][t] = __builtin_amdgcn_mfma_f32_16x16x32_bf16(a, curB, acc[h2][t], 0, 0, 0);
        }
      }
      curB = nextB; cb0 = nb0; cb1 = nb1; cb2 = nb2;
      if (i + 1 < cnt) __syncthreads();
    }
  } else {
    __syncthreads();   // match sync count? no other syncs in this branch yet
  }

  __syncthreads();   // all compute done; tiles dead -> reuse as zbuf
  float* zb = (float*)smem;
  {
    const int col = lane & 15, g = lane >> 4;
    if (col < 12) {
      #pragma unroll
      for (int h2 = 0; h2 < 2; ++h2)
        #pragma unroll
        for (int t = 0; t < 4; ++t)
          #pragma unroll
          for (int r = 0; r < 4; ++r)
            zb[((wid * 2 + h2) * 64 + t * 16 + g * 4 + r) * 13 + col] = acc[h2][t][r];
    }
  }
  __syncthreads();

  #pragma unroll
  for (int k2 = 0; k2 < 6; ++k2) {
    int u = tid + k2 * 256;
    int h = u / 192;
    int rem = u - h * 192;
    int co = rem >> 6, w = rem & 63;
    float y = (co == 0) ? bs0 : ((co == 1) ? bs1 : bs2);
    #pragma unroll
    for (int kw = 0; kw < 4; ++kw) {
      int wp_ = w + kw - 1;
      if (wp_ >= 0 && wp_ < 64) y += zb[(h * 64 + wp_) * 13 + co * 4 + kw];
    }
    int o = ((n * 8 + b) * 3 + co) * IMG + (ht * 8 + h) * 64 + w;
    float st = states[o], rv = res[o];
    out[o] = st + fabsf(rv) * (EQF - st) + y;
  }
}

extern "C" void kernel_launch(void* const* d_in, const int* in_sizes, int n_in,
                              void* d_out, int out_size, void* d_ws, size_t ws_size,
                              hipStream_t stream) {
  const float* states = (const float*)d_in[0];
  const float* noise  = (const float*)d_in[1];
  const float* conv_w = (const float*)d_in[2];
  const float* conv_b = (const float*)d_in[3];
  const float* res    = (const float*)d_in[4];
  const int*   src    = (const int*)d_in[5];
  const int*   dst    = (const int*)d_in[6];
  float* out = (float*)d_out;

  u16* actsI = (u16*)d_ws;                                   // 17,039,360 B
  u16* wfrag = (u16*)((char*)d_ws + 17039360);               //    525,312 B
  int* csr_off  = (int*)((char*)d_ws + 17564672);            // 65 ints
  int* csr_list = csr_off + 80;                              // 513 ints

  build_csr_k<<<1, 256, 0, stream>>>(dst, csr_off, csr_list);
  wfrag_k<<<(EE * 64 + 255) / 256, 256, 0, stream>>>(conv_w, wfrag);
  prep_k<<<(65 * 8 * 64 * 16) / 256, 256, 0, stream>>>(states, noise, actsI, out);
  conv_k<<<NN * BB * 8, 256, 0, stream>>>(states, res, actsI, wfrag, conv_b,
                                          src, csr_off, csr_list, out);
}